// Round 1
// baseline (1055.585 us; speedup 1.0000x reference)
//
#include <hip/hip_runtime.h>
#include <hip/hip_bf16.h>
#include <math.h>

#define NB 8          // batch
#define NN 1024       // nodes
#define NI 64         // input feat
#define EHC 4         // E*H
#define ND 128        // hidden
#define NO 64         // outputs
#define FIN1 512      // E*H*D
#define BN 8192       // B*N

// ---------------- embed: state0 = relu(nodes @ Wemb + bemb) ----------------
__global__ void embedk(const float* __restrict__ nodes, const float* __restrict__ Wemb,
                       const float* __restrict__ bemb, float* __restrict__ state0) {
    int row = blockIdx.x;            // 0..BN
    int d = threadIdx.x;             // 128
    __shared__ float nL[NI];
    if (threadIdx.x < NI) nL[threadIdx.x] = nodes[(size_t)row * NI + threadIdx.x];
    __syncthreads();
    float acc = bemb[d];
#pragma unroll
    for (int i = 0; i < NI; ++i) acc += nL[i] * Wemb[i * ND + d];
    state0[(size_t)row * ND + d] = fmaxf(acc, 0.f);
}

// ---------------- Wh GEMM: Wh[eh, row, d] = sum_k state[row,k] * W[eh,k,d] ----------------
template <int FIN, int NT>
__global__ void whgemm(const float* __restrict__ state, const float* __restrict__ W,
                       float* __restrict__ Wh) {
    int eh = blockIdx.y;
    int row0 = blockIdx.x * NT;
    int d = threadIdx.x;             // 128 threads
    __shared__ float sL[NT * FIN];
    for (int idx = threadIdx.x; idx < NT * FIN; idx += 128)
        sL[idx] = state[(size_t)row0 * FIN + idx];
    __syncthreads();
    float acc[NT];
#pragma unroll
    for (int r = 0; r < NT; ++r) acc[r] = 0.f;
    const float* Wp = W + (size_t)eh * FIN * ND + d;
#pragma unroll 4
    for (int k = 0; k < FIN; ++k) {
        float w = Wp[(size_t)k * ND];
#pragma unroll
        for (int r = 0; r < NT; ++r) acc[r] += sL[r * FIN + k] * w;
    }
#pragma unroll
    for (int r = 0; r < NT; ++r)
        Wh[((size_t)eh * BN + row0 + r) * ND + d] = acc[r];
}

// ---------------- s1/s2: per-row dots with attention vectors ----------------
__global__ void s1s2k(const float* __restrict__ Wh,
                      const float* __restrict__ a1w, const float* __restrict__ a1b,
                      const float* __restrict__ a2w, const float* __restrict__ a2b,
                      float* __restrict__ s1, float* __restrict__ s2) {
    int wave = threadIdx.x >> 6, lane = threadIdx.x & 63;
    int row = blockIdx.x * 4 + wave;       // 0..EHC*BN
    int eh = row >> 13;                    // row / BN
    const float* wr = Wh + (size_t)row * ND;
    float x0 = wr[lane], x1 = wr[lane + 64];
    float r1 = x0 * a1w[eh * ND + lane] + x1 * a1w[eh * ND + lane + 64];
    float r2 = x0 * a2w[eh * ND + lane] + x1 * a2w[eh * ND + lane + 64];
#pragma unroll
    for (int off = 32; off; off >>= 1) {
        r1 += __shfl_down(r1, off);
        r2 += __shfl_down(r2, off);
    }
    if (lane == 0) {
        s1[row] = r1 + a1b[eh];
        s2[row] = r2 + a2b[eh];
    }
}

// ---------------- column softmax stats: M[j],S[j] reduced over i ----------------
__global__ void colstatsk(const float* __restrict__ edges, const float* __restrict__ s1,
                          const float* __restrict__ s2, float* __restrict__ M,
                          float* __restrict__ S) {
    int b = blockIdx.y;
    int j0 = blockIdx.x * 64;
    int t = threadIdx.x;
    int h = t >> 7;
    int je = t & 127;
    int jl = je >> 1;
    int e = je & 1;
    int eh = e * 2 + h;
    int j = j0 + jl;
    __shared__ float s1L[EHC * NN];
    for (int idx = t; idx < EHC * NN; idx += 256) {
        int ee = idx >> 10;
        s1L[idx] = s1[((size_t)ee * NB + b) * NN + (idx & 1023)];
    }
    __syncthreads();
    float s2v = s2[((size_t)eh * NB + b) * NN + j];
    float m = -INFINITY, s = 0.f;
    const float* ep = edges + ((size_t)b * NN * NN + j) * 2 + e;  // + i*2048
    const float* s1p = s1L + eh * NN;
    for (int i = 0; i < NN; ++i) {
        float x = s1p[i] + s2v;
        x = x >= 0.f ? x : 0.2f * x;
        float a = x + ep[(size_t)i * (NN * 2)];
        float nm = fmaxf(m, a);
        s = s * __expf(m - nm) + __expf(a - nm);
        m = nm;
    }
    M[((size_t)eh * NB + b) * NN + j] = m;
    S[((size_t)eh * NB + b) * NN + j] = s;
}

// ---------------- fused msg: out = P @ (Wh / S) + sb  (+elu for layer 1) ----------------
__global__ void msgk(const float* __restrict__ edges, const float* __restrict__ Wh,
                     const float* __restrict__ s1, const float* __restrict__ s2,
                     const float* __restrict__ M, const float* __restrict__ S,
                     const float* __restrict__ sb, float* __restrict__ out, int mode) {
    int itile = blockIdx.x;
    int b = blockIdx.y;
    int eh = blockIdx.z;
    int e = eh >> 1;
    int i0 = itile * 64;
    int t = threadIdx.x;

    __shared__ float s1L[64];
    __shared__ float s2L[32], ML[32], SrL[32];
    __shared__ float sbL[ND];
    __shared__ float pL[64 * 33];
    __shared__ float whnL[32 * ND];

    if (t < 64) s1L[t] = s1[((size_t)eh * NB + b) * NN + i0 + t];
    if (t < ND) sbL[t] = sb[eh * ND + t];

    float acc[4][8];
#pragma unroll
    for (int r = 0; r < 4; ++r)
#pragma unroll
        for (int c = 0; c < 8; ++c) acc[r][c] = 0.f;

    int iq = t >> 4;   // 0..15 -> rows iq*4 .. iq*4+3
    int dq = t & 15;   // d = dq*8 .. dq*8+7
    const float* whbase = Wh + ((size_t)eh * BN + b * NN) * ND;
    const float* ebase = edges + (size_t)b * NN * NN * 2 + e;
    const float* svbase = s2 + ((size_t)eh * NB + b) * NN;
    const float* Mbase = M + ((size_t)eh * NB + b) * NN;
    const float* Sbase = S + ((size_t)eh * NB + b) * NN;

    for (int j0 = 0; j0 < NN; j0 += 32) {
        __syncthreads();
        if (t < 32) {
            s2L[t] = svbase[j0 + t];
            ML[t] = Mbase[j0 + t];
            SrL[t] = 1.f / Sbase[j0 + t];
        }
        __syncthreads();
        // stage normalized Wh tile
        for (int idx = t; idx < 32 * ND; idx += 256) {
            int jj = idx >> 7;
            whnL[idx] = whbase[(size_t)(j0 + jj) * ND + (idx & 127)] * SrL[jj];
        }
        // compute P tile
        {
            int jj = t & 31;
            int il0 = t >> 5;  // 0..7
#pragma unroll
            for (int k = 0; k < 8; ++k) {
                int il = il0 + k * 8;
                float x = s1L[il] + s2L[jj];
                x = x >= 0.f ? x : 0.2f * x;
                float a = x + ebase[(size_t)(i0 + il) * (NN * 2) + (j0 + jj) * 2];
                pL[il * 33 + jj] = __expf(a - ML[jj]);
            }
        }
        __syncthreads();
#pragma unroll 4
        for (int jj = 0; jj < 32; ++jj) {
            float pv[4];
#pragma unroll
            for (int r = 0; r < 4; ++r) pv[r] = pL[(iq * 4 + r) * 33 + jj];
            const float* wr = whnL + jj * ND + dq * 8;
            float4 w0 = *(const float4*)wr;
            float4 w1 = *(const float4*)(wr + 4);
#pragma unroll
            for (int r = 0; r < 4; ++r) {
                acc[r][0] += pv[r] * w0.x;
                acc[r][1] += pv[r] * w0.y;
                acc[r][2] += pv[r] * w0.z;
                acc[r][3] += pv[r] * w0.w;
                acc[r][4] += pv[r] * w1.x;
                acc[r][5] += pv[r] * w1.y;
                acc[r][6] += pv[r] * w1.z;
                acc[r][7] += pv[r] * w1.w;
            }
        }
    }
    // epilogue
#pragma unroll
    for (int r = 0; r < 4; ++r) {
        int i = i0 + iq * 4 + r;
#pragma unroll
        for (int c = 0; c < 8; ++c) {
            int d = dq * 8 + c;
            float v = acc[r][c] + sbL[d];
            if (mode == 0) {
                // layer 0: write concat layout (B,N,EH*D)
                out[((size_t)(b * NN + i)) * FIN1 + eh * ND + d] = v;
            } else {
                // layer 1: elu, write (EH,B,N,D)
                v = v > 0.f ? v : expm1f(v);
                out[(((size_t)eh * NB + b) * NN + i) * ND + d] = v;
            }
        }
    }
}

// ---------------- mean over eh ----------------
__global__ void reducek(const float* __restrict__ m1, float* __restrict__ stateF) {
    size_t idx = (size_t)blockIdx.x * 256 + threadIdx.x;  // over BN*ND
    const size_t str = (size_t)BN * ND;
    stateF[idx] = 0.25f * (m1[idx] + m1[idx + str] + m1[idx + 2 * str] + m1[idx + 3 * str]);
}

// ---------------- final: out = stateF @ Wout + bout ----------------
__global__ void finalk(const float* __restrict__ stateF, const float* __restrict__ Wout,
                       const float* __restrict__ bout, float* __restrict__ out) {
    int row0 = blockIdx.x * 16;
    int t = threadIdx.x;
    __shared__ float sF[16 * ND];
    __shared__ float wL[ND * NO];
    for (int idx = t; idx < 16 * ND; idx += 256) sF[idx] = stateF[(size_t)row0 * ND + idx];
    for (int idx = t; idx < ND * NO; idx += 256) wL[idx] = Wout[idx];
    __syncthreads();
    int o = t & 63;
    int rr = t >> 6;  // 0..3
    float bo = bout[o];
#pragma unroll
    for (int q = 0; q < 4; ++q) {
        int r = rr * 4 + q;
        float acc = 0.f;
#pragma unroll 4
        for (int d = 0; d < ND; ++d) acc += sF[r * ND + d] * wL[d * NO + o];
        out[(size_t)(row0 + r) * NO + o] = acc + bo;
    }
}

extern "C" void kernel_launch(void* const* d_in, const int* in_sizes, int n_in,
                              void* d_out, int out_size, void* d_ws, size_t ws_size,
                              hipStream_t stream) {
    const float* nodes = (const float*)d_in[0];
    const float* edges = (const float*)d_in[1];
    const float* Wemb = (const float*)d_in[2];
    const float* bemb = (const float*)d_in[3];
    const float* W0 = (const float*)d_in[4];
    const float* A1w0 = (const float*)d_in[5];
    const float* A1b0 = (const float*)d_in[6];
    const float* A2w0 = (const float*)d_in[7];
    const float* A2b0 = (const float*)d_in[8];
    const float* SB0 = (const float*)d_in[9];
    const float* W1 = (const float*)d_in[10];
    const float* A1w1 = (const float*)d_in[11];
    const float* A1b1 = (const float*)d_in[12];
    const float* A2w1 = (const float*)d_in[13];
    const float* A2b1 = (const float*)d_in[14];
    const float* SB1 = (const float*)d_in[15];
    const float* Wout = (const float*)d_in[16];
    const float* bout = (const float*)d_in[17];
    float* out = (float*)d_out;

    float* ws = (float*)d_ws;
    float* state0 = ws;                      // BN*ND          = 1,048,576
    float* Wh = state0 + (size_t)BN * ND;    // EHC*BN*ND      = 4,194,304
    float* s1b = Wh + (size_t)EHC * BN * ND; // EHC*BN         = 32,768
    float* s2b = s1b + EHC * BN;
    float* Mb = s2b + EHC * BN;
    float* Sb = Mb + EHC * BN;
    float* state1 = Sb + EHC * BN;           // BN*FIN1        = 4,194,304
    float* m1 = state1 + (size_t)BN * FIN1;  // EHC*BN*ND      = 4,194,304
    float* stateF = state0;                  // reuse (state0 dead after layer-0 GEMM)

    // embed
    embedk<<<BN, ND, 0, stream>>>(nodes, Wemb, bemb, state0);
    // layer 0
    whgemm<ND, 16><<<dim3(BN / 16, EHC), 128, 0, stream>>>(state0, W0, Wh);
    s1s2k<<<(EHC * BN) / 4, 256, 0, stream>>>(Wh, A1w0, A1b0, A2w0, A2b0, s1b, s2b);
    colstatsk<<<dim3(NN / 64, NB), 256, 0, stream>>>(edges, s1b, s2b, Mb, Sb);
    msgk<<<dim3(NN / 64, NB, EHC), 256, 0, stream>>>(edges, Wh, s1b, s2b, Mb, Sb, SB0,
                                                     state1, 0);
    // layer 1
    whgemm<FIN1, 8><<<dim3(BN / 8, EHC), 128, 0, stream>>>(state1, W1, Wh);
    s1s2k<<<(EHC * BN) / 4, 256, 0, stream>>>(Wh, A1w1, A1b1, A2w1, A2b1, s1b, s2b);
    colstatsk<<<dim3(NN / 64, NB), 256, 0, stream>>>(edges, s1b, s2b, Mb, Sb);
    msgk<<<dim3(NN / 64, NB, EHC), 256, 0, stream>>>(edges, Wh, s1b, s2b, Mb, Sb, SB1, m1, 1);
    // head
    reducek<<<(BN * ND) / 256, 256, 0, stream>>>(m1, stateF);
    finalk<<<BN / 16, 256, 0, stream>>>(stateF, Wout, bout, out);
}

// Round 2
// 393.666 us; speedup vs baseline: 2.6814x; 2.6814x over previous
//
#include <hip/hip_runtime.h>
#include <hip/hip_bf16.h>
#include <math.h>

#define NB 8          // batch
#define NN 1024       // nodes
#define NI 64         // input feat
#define EHC 4         // E*H
#define ND 128        // hidden
#define NO 64         // outputs
#define FIN1 512      // E*H*D
#define BN 8192       // B*N

typedef __attribute__((ext_vector_type(8))) short short8;
typedef __attribute__((ext_vector_type(4))) float f32x4;

__device__ __forceinline__ unsigned short f2bf(float f) {
    union { float f; unsigned u; } v; v.f = f;
    unsigned r = v.u + 0x7FFF + ((v.u >> 16) & 1);
    return (unsigned short)(r >> 16);
}
__device__ __forceinline__ float bf2f(unsigned short h) {
    union { unsigned u; float f; } v; v.u = ((unsigned)h) << 16;
    return v.f;
}

// ---------------- prep: transpose W0,W1 -> bf16 WT[eh][d][k] ----------------
__global__ void prepTk(const float* __restrict__ W0, const float* __restrict__ W1,
                       unsigned short* __restrict__ W0T, unsigned short* __restrict__ W1T) {
    int idx = blockIdx.x * 256 + threadIdx.x;
    if (idx < EHC * ND * ND) {
        int eh = idx >> 14, d = (idx >> 7) & 127, k = idx & 127;
        W0T[idx] = f2bf(W0[((size_t)(eh * ND + k)) * ND + d]);
    }
    int idx1 = idx - EHC * ND * ND;
    if (idx1 >= 0 && idx1 < EHC * ND * FIN1) {
        int eh = idx1 >> 16;
        int r = idx1 & 65535;
        int d = r >> 9, k = r & 511;
        W1T[idx1] = f2bf(W1[((size_t)(eh * FIN1 + k)) * ND + d]);
    }
}

// ---------------- embed: state0 = relu(nodes @ Wemb + bemb), bf16 out ----------------
__global__ void embedk(const float* __restrict__ nodes, const float* __restrict__ Wemb,
                       const float* __restrict__ bemb, unsigned short* __restrict__ state0) {
    int row = blockIdx.x;
    int d = threadIdx.x;
    __shared__ float nL[NI];
    if (d < NI) nL[d] = nodes[(size_t)row * NI + d];
    __syncthreads();
    float acc = bemb[d];
#pragma unroll
    for (int i = 0; i < NI; ++i) acc += nL[i] * Wemb[i * ND + d];
    state0[(size_t)row * ND + d] = f2bf(fmaxf(acc, 0.f));
}

// ---------------- MFMA filter GEMM: WhT[eh][b][d][i] = sum_k state[row,k]*W[eh,k,d] ----
// A = state rows (M=i), B = WT[eh][d][k] (N=d). No LDS, no barriers.
template <int FIN>
__global__ __launch_bounds__(256) void whgemmk(const unsigned short* __restrict__ state,
                                               const unsigned short* __restrict__ WT,
                                               unsigned short* __restrict__ WhT) {
    int eh = blockIdx.y;
    int row0 = blockIdx.x * 64;
    int t = threadIdx.x;
    int w = t >> 6, lane = t & 63;
    int m = lane & 15, quad = lane >> 4;

    f32x4 acc[4][2];
#pragma unroll
    for (int mt = 0; mt < 4; ++mt)
#pragma unroll
        for (int nt = 0; nt < 2; ++nt) acc[mt][nt] = (f32x4){0.f, 0.f, 0.f, 0.f};

    const unsigned short* Ab = state + (size_t)(row0 + m) * FIN + quad * 8;
    const unsigned short* Bb = WT + ((size_t)eh * ND + w * 32 + m) * FIN + quad * 8;
#pragma unroll
    for (int k0 = 0; k0 < FIN; k0 += 32) {
        short8 a[4], b[2];
#pragma unroll
        for (int mt = 0; mt < 4; ++mt)
            a[mt] = *(const short8*)(Ab + (size_t)mt * 16 * FIN + k0);
#pragma unroll
        for (int nt = 0; nt < 2; ++nt)
            b[nt] = *(const short8*)(Bb + (size_t)nt * 16 * FIN + k0);
#pragma unroll
        for (int mt = 0; mt < 4; ++mt)
#pragma unroll
            for (int nt = 0; nt < 2; ++nt)
                acc[mt][nt] =
                    __builtin_amdgcn_mfma_f32_16x16x32_bf16(a[mt], b[nt], acc[mt][nt], 0, 0, 0);
    }
    int b_ = row0 >> 10, i0b = row0 & 1023;
    // C layout: col(lane&15)=d within nt-tile, row(quad*4+r)=state row -> 4 consecutive i
#pragma unroll
    for (int mt = 0; mt < 4; ++mt)
#pragma unroll
        for (int nt = 0; nt < 2; ++nt) {
            int d = w * 32 + nt * 16 + m;
            int i = i0b + mt * 16 + quad * 4;
            union { unsigned short us[4]; unsigned long long u64; } pk;
#pragma unroll
            for (int r = 0; r < 4; ++r) pk.us[r] = f2bf(acc[mt][nt][r]);
            *(unsigned long long*)(WhT + (((size_t)eh * NB + b_) * ND + d) * NN + i) = pk.u64;
        }
}

// ---------------- s1/s2 from WhT (coalesced column reads) ----------------
__global__ void s1s2k(const unsigned short* __restrict__ WhT,
                      const float* __restrict__ a1w, const float* __restrict__ a1b,
                      const float* __restrict__ a2w, const float* __restrict__ a2b,
                      float* __restrict__ s1, float* __restrict__ s2) {
    int gid = blockIdx.x * 256 + threadIdx.x;   // over EHC*BN
    int eh = gid >> 13;
    int b = (gid >> 10) & 7;
    int i = gid & 1023;
    const unsigned short* wp = WhT + ((size_t)(eh * NB + b) * ND) * NN + i;
    float r1 = 0.f, r2 = 0.f;
#pragma unroll 4
    for (int d = 0; d < ND; ++d) {
        float wv = bf2f(wp[(size_t)d * NN]);
        r1 += wv * a1w[eh * ND + d];
        r2 += wv * a2w[eh * ND + d];
    }
    s1[gid] = r1 + a1b[eh];
    s2[gid] = r2 + a2b[eh];
}

// ---------------- column softmax stats over i: M[j], S[j] ----------------
__global__ __launch_bounds__(256) void colstatsk(const float* __restrict__ edges,
                                                 const float* __restrict__ s1,
                                                 const float* __restrict__ s2,
                                                 float* __restrict__ M, float* __restrict__ S) {
    int eh = blockIdx.x, jt = blockIdx.y, b = blockIdx.z;
    int e = eh >> 1;
    int t = threadIdx.x;
    int tj = t & 63, tic = t >> 6;
    int j = jt * 64 + tj;
    int base = (eh * NB + b) * NN;
    __shared__ float s1L[NN];
    __shared__ float pm[4][64], ps[4][64];
    for (int idx = t; idx < NN; idx += 256) s1L[idx] = s1[base + idx];
    __syncthreads();
    float s2v = s2[base + j];
    const float2* ep = (const float2*)edges + ((size_t)(b * NN + tic * 256)) * NN + j;
    float m = -INFINITY, s = 0.f;
    for (int ii = 0; ii < 256; ++ii) {
        float2 ev = ep[(size_t)ii * NN];
        float edge = e ? ev.y : ev.x;
        float x = s1L[tic * 256 + ii] + s2v;
        x = x >= 0.f ? x : 0.2f * x;
        float a = x + edge;
        float nm = fmaxf(m, a);
        s = s * __expf(m - nm) + __expf(a - nm);
        m = nm;
    }
    pm[tic][tj] = m;
    ps[tic][tj] = s;
    __syncthreads();
    if (t < 64) {
        float m0 = pm[0][t], m1v = pm[1][t], m2 = pm[2][t], m3 = pm[3][t];
        float mm = fmaxf(fmaxf(m0, m1v), fmaxf(m2, m3));
        float ss = ps[0][t] * __expf(m0 - mm) + ps[1][t] * __expf(m1v - mm) +
                   ps[2][t] * __expf(m2 - mm) + ps[3][t] * __expf(m3 - mm);
        M[base + jt * 64 + t] = mm;
        S[base + jt * 64 + t] = ss;
    }
}

// ---------------- fused msg: C[d][i] = sum_j Wh[j,d] * P[i,j],  MFMA ----------------
// A = WhT rows (M=d), B = P^T from LDS (N=i). P computed on the fly in bf16.
__global__ __launch_bounds__(256) void msgk(const float* __restrict__ edges,
                                            const unsigned short* __restrict__ WhT,
                                            const float* __restrict__ s1,
                                            const float* __restrict__ s2,
                                            const float* __restrict__ M,
                                            const float* __restrict__ S,
                                            const float* __restrict__ sb,
                                            unsigned short* __restrict__ out0,
                                            float* __restrict__ out1, int mode) {
    int eh = blockIdx.x, itile = blockIdx.y, b = blockIdx.z;
    int e = eh >> 1;
    int i0 = itile * 64;
    int t = threadIdx.x;
    int w = t >> 6, lane = t & 63;
    int n = lane & 15, quad = lane >> 4;
    int jl = t & 31, ib = t >> 5;   // P-compute mapping: 8 rows x 1 col per thread

    __shared__ float stL[NN * 4];                 // {s2, M, 1/S, pad} per j
    __shared__ unsigned short pA[2][64 * 40];     // P tile, row stride 40 (pad)

    int base = (eh * NB + b) * NN;
    for (int idx = t; idx < NN; idx += 256) {
        float4 st;
        st.x = s2[base + idx];
        st.y = M[base + idx];
        st.z = 1.f / S[base + idx];
        st.w = 0.f;
        *(float4*)&stL[idx * 4] = st;
    }
    // preload this thread's 8 s1 values (rows fixed across K-loop)
    f32x4 sv0 = *(const f32x4*)(s1 + base + i0 + ib * 8);
    f32x4 sv1 = *(const f32x4*)(s1 + base + i0 + ib * 8 + 4);
    float s1r[8];
#pragma unroll
    for (int q = 0; q < 4; ++q) { s1r[q] = sv0[q]; s1r[q + 4] = sv1[q]; }

    f32x4 acc[2][4];
#pragma unroll
    for (int mt = 0; mt < 2; ++mt)
#pragma unroll
        for (int nt = 0; nt < 4; ++nt) acc[mt][nt] = (f32x4){0.f, 0.f, 0.f, 0.f};

    const unsigned short* Ab =
        WhT + ((size_t)(eh * NB + b) * ND + (w * 32 + n)) * NN + quad * 8;
    const float2* ep = (const float2*)edges + (size_t)(b * NN + i0 + ib * 8) * NN + jl;
    __syncthreads();  // stL ready

    for (int j0 = 0; j0 < NN; j0 += 32) {
        int buf = (j0 >> 5) & 1;
        float4 st = *(const float4*)&stL[(j0 + jl) * 4];
#pragma unroll
        for (int q = 0; q < 8; ++q) {
            float2 ev = ep[(size_t)q * NN + j0];
            float edge = e ? ev.y : ev.x;
            float x = s1r[q] + st.x;
            x = x >= 0.f ? x : 0.2f * x;
            float a = x + edge;
            pA[buf][(ib * 8 + q) * 40 + jl] = f2bf(__expf(a - st.y) * st.z);
        }
        __syncthreads();  // pA[buf] visible; prev MFMA (other buf) done
        short8 av[2], bv[4];
#pragma unroll
        for (int mt = 0; mt < 2; ++mt)
            av[mt] = *(const short8*)(Ab + (size_t)mt * 16 * NN + j0);
#pragma unroll
        for (int nt = 0; nt < 4; ++nt)
            bv[nt] = *(const short8*)&pA[buf][(nt * 16 + n) * 40 + quad * 8];
#pragma unroll
        for (int mt = 0; mt < 2; ++mt)
#pragma unroll
            for (int nt = 0; nt < 4; ++nt)
                acc[mt][nt] =
                    __builtin_amdgcn_mfma_f32_16x16x32_bf16(av[mt], bv[nt], acc[mt][nt], 0, 0, 0);
    }

    // epilogue: C row(quad*4+r)=d, col(lane&15)=i-local -> 4 consecutive d per lane
#pragma unroll
    for (int mt = 0; mt < 2; ++mt) {
        int d0 = w * 32 + mt * 16 + quad * 4;
        f32x4 sbv = *(const f32x4*)&sb[eh * ND + d0];
#pragma unroll
        for (int nt = 0; nt < 4; ++nt) {
            int i = i0 + nt * 16 + n;
            if (mode == 0) {
                union { unsigned short us[4]; unsigned long long u64; } pk;
#pragma unroll
                for (int r = 0; r < 4; ++r) pk.us[r] = f2bf(acc[mt][nt][r] + sbv[r]);
                *(unsigned long long*)(out0 + (size_t)(b * NN + i) * FIN1 + eh * ND + d0) =
                    pk.u64;
            } else {
                f32x4 vv;
#pragma unroll
                for (int r = 0; r < 4; ++r) {
                    float v = acc[mt][nt][r] + sbv[r];
                    vv[r] = v > 0.f ? v : expm1f(v);
                }
                *(f32x4*)(out1 + ((size_t)(eh * NB + b) * NN + i) * ND + d0) = vv;
            }
        }
    }
}

// ---------------- mean over eh ----------------
__global__ void reducek(const float* __restrict__ m1, float* __restrict__ stateF) {
    size_t idx = (size_t)blockIdx.x * 256 + threadIdx.x;
    const size_t str = (size_t)BN * ND;
    stateF[idx] = 0.25f * (m1[idx] + m1[idx + str] + m1[idx + 2 * str] + m1[idx + 3 * str]);
}

// ---------------- final: out = stateF @ Wout + bout ----------------
__global__ void finalk(const float* __restrict__ stateF, const float* __restrict__ Wout,
                       const float* __restrict__ bout, float* __restrict__ out) {
    int row0 = blockIdx.x * 16;
    int t = threadIdx.x;
    __shared__ float sF[16 * ND];
    __shared__ float wL[ND * NO];
    for (int idx = t; idx < 16 * ND; idx += 256) sF[idx] = stateF[(size_t)row0 * ND + idx];
    for (int idx = t; idx < ND * NO; idx += 256) wL[idx] = Wout[idx];
    __syncthreads();
    int o = t & 63;
    int rr = t >> 6;
    float bo = bout[o];
#pragma unroll
    for (int q = 0; q < 4; ++q) {
        int r = rr * 4 + q;
        float acc = 0.f;
#pragma unroll 4
        for (int d = 0; d < ND; ++d) acc += sF[r * ND + d] * wL[d * NO + o];
        out[(size_t)(row0 + r) * NO + o] = acc + bo;
    }
}

extern "C" void kernel_launch(void* const* d_in, const int* in_sizes, int n_in,
                              void* d_out, int out_size, void* d_ws, size_t ws_size,
                              hipStream_t stream) {
    const float* nodes = (const float*)d_in[0];
    const float* edges = (const float*)d_in[1];
    const float* Wemb = (const float*)d_in[2];
    const float* bemb = (const float*)d_in[3];
    const float* W0 = (const float*)d_in[4];
    const float* A1w0 = (const float*)d_in[5];
    const float* A1b0 = (const float*)d_in[6];
    const float* A2w0 = (const float*)d_in[7];
    const float* A2b0 = (const float*)d_in[8];
    const float* SB0 = (const float*)d_in[9];
    const float* W1 = (const float*)d_in[10];
    const float* A1w1 = (const float*)d_in[11];
    const float* A1b1 = (const float*)d_in[12];
    const float* A2w1 = (const float*)d_in[13];
    const float* A2b1 = (const float*)d_in[14];
    const float* SB1 = (const float*)d_in[15];
    const float* Wout = (const float*)d_in[16];
    const float* bout = (const float*)d_in[17];
    float* out = (float*)d_out;

    char* p = (char*)d_ws;
    auto alloc = [&](size_t bytes) {
        char* r = p;
        p += (bytes + 255) & ~(size_t)255;
        return r;
    };
    unsigned short* state0 = (unsigned short*)alloc((size_t)BN * ND * 2);
    unsigned short* W0T = (unsigned short*)alloc((size_t)EHC * ND * ND * 2);
    unsigned short* W1T = (unsigned short*)alloc((size_t)EHC * ND * FIN1 * 2);
    unsigned short* WhT = (unsigned short*)alloc((size_t)EHC * BN * ND * 2);
    unsigned short* state1 = (unsigned short*)alloc((size_t)BN * FIN1 * 2);
    float* s1b = (float*)alloc((size_t)EHC * BN * 4);
    float* s2b = (float*)alloc((size_t)EHC * BN * 4);
    float* Mb = (float*)alloc((size_t)EHC * BN * 4);
    float* Sb = (float*)alloc((size_t)EHC * BN * 4);
    float* m1 = (float*)alloc((size_t)EHC * BN * ND * 4);
    float* stateF = (float*)alloc((size_t)BN * ND * 4);

    prepTk<<<1280, 256, 0, stream>>>(W0, W1, W0T, W1T);
    embedk<<<BN, ND, 0, stream>>>(nodes, Wemb, bemb, state0);
    // layer 0
    whgemmk<ND><<<dim3(BN / 64, EHC), 256, 0, stream>>>(state0, W0T, WhT);
    s1s2k<<<EHC * BN / 256, 256, 0, stream>>>(WhT, A1w0, A1b0, A2w0, A2b0, s1b, s2b);
    colstatsk<<<dim3(EHC, NN / 64, NB), 256, 0, stream>>>(edges, s1b, s2b, Mb, Sb);
    msgk<<<dim3(EHC, NN / 64, NB), 256, 0, stream>>>(edges, WhT, s1b, s2b, Mb, Sb, SB0,
                                                     state1, m1, 0);
    // layer 1
    whgemmk<FIN1><<<dim3(BN / 64, EHC), 256, 0, stream>>>(state1, W1T, WhT);
    s1s2k<<<EHC * BN / 256, 256, 0, stream>>>(WhT, A1w1, A1b1, A2w1, A2b1, s1b, s2b);
    colstatsk<<<dim3(EHC, NN / 64, NB), 256, 0, stream>>>(edges, s1b, s2b, Mb, Sb);
    msgk<<<dim3(EHC, NN / 64, NB), 256, 0, stream>>>(edges, WhT, s1b, s2b, Mb, Sb, SB1,
                                                     state1, m1, 1);
    // head
    reducek<<<(BN * ND) / 256, 256, 0, stream>>>(m1, stateF);
    finalk<<<BN / 16, 256, 0, stream>>>(stateF, Wout, bout, out);
}

// Round 3
// 309.215 us; speedup vs baseline: 3.4138x; 1.2731x over previous
//
#include <hip/hip_runtime.h>
#include <hip/hip_bf16.h>
#include <math.h>

#define NB 8          // batch
#define NN 1024       // nodes
#define NI 64         // input feat
#define EHC 4         // E*H
#define ND 128        // hidden
#define NO 64         // outputs
#define FIN1 512      // E*H*D
#define BN 8192       // B*N

typedef __attribute__((ext_vector_type(8))) short short8;
typedef __attribute__((ext_vector_type(4))) float f32x4;

__device__ __forceinline__ unsigned short f2bf(float f) {
    union { float f; unsigned u; } v; v.f = f;
    unsigned r = v.u + 0x7FFF + ((v.u >> 16) & 1);
    return (unsigned short)(r >> 16);
}
__device__ __forceinline__ float bf2f(unsigned short h) {
    union { unsigned u; float f; } v; v.u = ((unsigned)h) << 16;
    return v.f;
}

// ---------------- prep: transpose W0,W1 -> bf16 WT[eh][d][k] ----------------
__global__ void prepTk(const float* __restrict__ W0, const float* __restrict__ W1,
                       unsigned short* __restrict__ W0T, unsigned short* __restrict__ W1T) {
    int idx = blockIdx.x * 256 + threadIdx.x;
    if (idx < EHC * ND * ND) {
        int eh = idx >> 14, d = (idx >> 7) & 127, k = idx & 127;
        W0T[idx] = f2bf(W0[((size_t)(eh * ND + k)) * ND + d]);
    }
    int idx1 = idx - EHC * ND * ND;
    if (idx1 >= 0 && idx1 < EHC * ND * FIN1) {
        int eh = idx1 >> 16;
        int r = idx1 & 65535;
        int d = r >> 9, k = r & 511;
        W1T[idx1] = f2bf(W1[((size_t)(eh * FIN1 + k)) * ND + d]);
    }
}

// ---------------- embed: state0 = relu(nodes @ Wemb + bemb), bf16 out ----------------
__global__ __launch_bounds__(256) void embedk(const float* __restrict__ nodes,
                                              const float* __restrict__ Wemb,
                                              const float* __restrict__ bemb,
                                              unsigned short* __restrict__ state0) {
    int row0 = blockIdx.x * 16;
    int t = threadIdx.x;
    __shared__ float wL[NI * ND];
    __shared__ float nL[16 * NI];
    for (int idx = t; idx < NI * ND; idx += 256) wL[idx] = Wemb[idx];
    for (int idx = t; idx < 16 * NI; idx += 256) nL[idx] = nodes[(size_t)row0 * NI + idx];
    __syncthreads();
    int d = t & 127, rh = t >> 7;
    float b0 = bemb[d];
    float acc[8];
#pragma unroll
    for (int r = 0; r < 8; ++r) acc[r] = b0;
#pragma unroll 8
    for (int k = 0; k < NI; ++k) {
        float w = wL[k * ND + d];
#pragma unroll
        for (int r = 0; r < 8; ++r) acc[r] += nL[(rh * 8 + r) * NI + k] * w;
    }
#pragma unroll
    for (int r = 0; r < 8; ++r)
        state0[(size_t)(row0 + rh * 8 + r) * ND + d] = f2bf(fmaxf(acc[r], 0.f));
}

// ---------------- MFMA filter GEMM: WhT[eh][b][d][i] = sum_k state[row,k]*W[eh,k,d] ----
template <int FIN>
__global__ __launch_bounds__(256) void whgemmk(const unsigned short* __restrict__ state,
                                               const unsigned short* __restrict__ WT,
                                               unsigned short* __restrict__ WhT) {
    int eh = blockIdx.y;
    int row0 = blockIdx.x * 64;
    int t = threadIdx.x;
    int w = t >> 6, lane = t & 63;
    int m = lane & 15, quad = lane >> 4;

    f32x4 acc[4][2];
#pragma unroll
    for (int mt = 0; mt < 4; ++mt)
#pragma unroll
        for (int nt = 0; nt < 2; ++nt) acc[mt][nt] = (f32x4){0.f, 0.f, 0.f, 0.f};

    const unsigned short* Ab = state + (size_t)(row0 + m) * FIN + quad * 8;
    const unsigned short* Bb = WT + ((size_t)eh * ND + w * 32 + m) * FIN + quad * 8;
#pragma unroll
    for (int k0 = 0; k0 < FIN; k0 += 32) {
        short8 a[4], b[2];
#pragma unroll
        for (int mt = 0; mt < 4; ++mt)
            a[mt] = *(const short8*)(Ab + (size_t)mt * 16 * FIN + k0);
#pragma unroll
        for (int nt = 0; nt < 2; ++nt)
            b[nt] = *(const short8*)(Bb + (size_t)nt * 16 * FIN + k0);
#pragma unroll
        for (int mt = 0; mt < 4; ++mt)
#pragma unroll
            for (int nt = 0; nt < 2; ++nt)
                acc[mt][nt] =
                    __builtin_amdgcn_mfma_f32_16x16x32_bf16(a[mt], b[nt], acc[mt][nt], 0, 0, 0);
    }
    int b_ = row0 >> 10, i0b = row0 & 1023;
#pragma unroll
    for (int mt = 0; mt < 4; ++mt)
#pragma unroll
        for (int nt = 0; nt < 2; ++nt) {
            int d = w * 32 + nt * 16 + m;
            int i = i0b + mt * 16 + quad * 4;
            union { unsigned short us[4]; unsigned long long u64; } pk;
#pragma unroll
            for (int r = 0; r < 4; ++r) pk.us[r] = f2bf(acc[mt][nt][r]);
            *(unsigned long long*)(WhT + (((size_t)eh * NB + b_) * ND + d) * NN + i) = pk.u64;
        }
}

// ---------------- s1/s2 from WhT (d-split + LDS combine) ----------------
__global__ __launch_bounds__(256) void s1s2k(const unsigned short* __restrict__ WhT,
                                             const float* __restrict__ a1w,
                                             const float* __restrict__ a1b,
                                             const float* __restrict__ a2w,
                                             const float* __restrict__ a2b,
                                             float* __restrict__ s1, float* __restrict__ s2) {
    int bx = blockIdx.x;            // 512 = 32 slices * 16 itiles
    int ehb = bx >> 4;              // eh*NB+b
    int eh = ehb >> 3;
    int it = bx & 15;
    int i0 = it * 64;
    int t = threadIdx.x;
    int il = t & 63, dc = t >> 6;
    const unsigned short* wp = WhT + ((size_t)ehb * ND + dc * 32) * NN + i0 + il;
    float r1 = 0.f, r2 = 0.f;
#pragma unroll 8
    for (int dd = 0; dd < 32; ++dd) {
        int d = dc * 32 + dd;
        float wv = bf2f(wp[(size_t)dd * NN]);
        r1 += wv * a1w[eh * ND + d];
        r2 += wv * a2w[eh * ND + d];
    }
    __shared__ float red[2][4][64];
    red[0][dc][il] = r1;
    red[1][dc][il] = r2;
    __syncthreads();
    if (t < 64) {
        s1[(size_t)ehb * NN + i0 + t] =
            red[0][0][t] + red[0][1][t] + red[0][2][t] + red[0][3][t] + a1b[eh];
    } else if (t < 128) {
        int il2 = t - 64;
        s2[(size_t)ehb * NN + i0 + il2] =
            red[1][0][il2] + red[1][1][il2] + red[1][2][il2] + red[1][3][il2] + a2b[eh];
    }
}

// ---------------- column sums (no-max softmax): Spart[ic][eh][b][j] ----------------
__global__ __launch_bounds__(256) void colsumk(const float* __restrict__ edges,
                                               const float* __restrict__ s1,
                                               const float* __restrict__ s2,
                                               float* __restrict__ Spart) {
    int jt = blockIdx.x, b = blockIdx.y, ic = blockIdx.z;
    int t = threadIdx.x;
    int jl = t & 63, is = t >> 6;
    int j = jt * 64 + jl;
    __shared__ float s1L[4][256];
    for (int idx = t; idx < 1024; idx += 256) {
        int eh = idx >> 8;
        s1L[eh][idx & 255] = s1[((size_t)eh * NB + b) * NN + ic * 256 + (idx & 255)];
    }
    __syncthreads();
    float s2v[4], acc4[4];
#pragma unroll
    for (int eh = 0; eh < 4; ++eh) {
        s2v[eh] = s2[((size_t)eh * NB + b) * NN + j];
        acc4[eh] = 0.f;
    }
    const float2* ep = (const float2*)edges + ((size_t)(b * NN + ic * 256 + is * 64)) * NN + j;
#pragma unroll 4
    for (int ii = 0; ii < 64; ++ii) {
        float2 ev = ep[(size_t)ii * NN];
        int il = is * 64 + ii;
#pragma unroll
        for (int eh = 0; eh < 4; ++eh) {
            float x = s1L[eh][il] + s2v[eh];
            x = x >= 0.f ? x : 0.2f * x;
            float a = x + (eh < 2 ? ev.x : ev.y);
            acc4[eh] += __expf(a);
        }
    }
    __shared__ float red[4][4][64];   // [is][eh][jl]
#pragma unroll
    for (int eh = 0; eh < 4; ++eh) red[is][eh][jl] = acc4[eh];
    __syncthreads();
    if (t < 256) {
        int eho = t >> 6, jlo = t & 63;
        float Sv = red[0][eho][jlo] + red[1][eho][jlo] + red[2][eho][jlo] + red[3][eho][jlo];
        Spart[(((size_t)ic * EHC + eho) * NB + b) * NN + jt * 64 + jlo] = Sv;
    }
}

// ---------------- fused msg: C[d][i] = sum_j Wh[j,d] * P[i,j], pipelined MFMA ----------
__global__ __launch_bounds__(256, 2) void msgk(const float* __restrict__ edges,
                                               const unsigned short* __restrict__ WhT,
                                               const float* __restrict__ s1,
                                               const float* __restrict__ s2,
                                               const float* __restrict__ Spart,
                                               const float* __restrict__ sb,
                                               unsigned short* __restrict__ out0,
                                               float* __restrict__ out1, int mode) {
    int eh = blockIdx.x, itile = blockIdx.y, b = blockIdx.z;
    int e = eh >> 1;
    int i0 = itile * 64;
    int t = threadIdx.x;
    int w = t >> 6, lane = t & 63;
    int n = lane & 15, quad = lane >> 4;
    int jl = t & 63, ib = w;     // P-compute: 16 rows x 1 col per thread

    __shared__ float2 stL[NN];               // {s2, 1/S} per j
    __shared__ unsigned short pA[2][64 * 72];

    int base = (eh * NB + b) * NN;
    for (int idx = t; idx < NN; idx += 256) {
        float Sv = Spart[((size_t)(0 * EHC + eh) * NB + b) * NN + idx] +
                   Spart[((size_t)(1 * EHC + eh) * NB + b) * NN + idx] +
                   Spart[((size_t)(2 * EHC + eh) * NB + b) * NN + idx] +
                   Spart[((size_t)(3 * EHC + eh) * NB + b) * NN + idx];
        stL[idx] = make_float2(s2[base + idx], 1.f / Sv);
    }
    float s1r[16];
    {
        const f32x4* sp = (const f32x4*)(s1 + base + i0 + ib * 16);
#pragma unroll
        for (int q4 = 0; q4 < 4; ++q4) {
            f32x4 v = sp[q4];
#pragma unroll
            for (int r = 0; r < 4; ++r) s1r[q4 * 4 + r] = v[r];
        }
    }

    f32x4 acc[2][4];
#pragma unroll
    for (int mt = 0; mt < 2; ++mt)
#pragma unroll
        for (int nt = 0; nt < 4; ++nt) acc[mt][nt] = (f32x4){0.f, 0.f, 0.f, 0.f};

    const unsigned short* Ab =
        WhT + ((size_t)(eh * NB + b) * ND + (w * 32 + n)) * NN + quad * 8;
    const float2* ep = (const float2*)edges + (size_t)(b * NN + i0 + ib * 16) * NN + jl;
    __syncthreads();  // stL ready

    float2 evA[16], evB[16];
    short8 aA[4], aB[4];

    auto loadE = [&](float2* ev, int j0) {
#pragma unroll
        for (int q = 0; q < 16; ++q) ev[q] = ep[(size_t)q * NN + j0];
    };
    auto loadA = [&](short8* av, int j0) {
#pragma unroll
        for (int mt = 0; mt < 2; ++mt)
#pragma unroll
            for (int kt = 0; kt < 2; ++kt)
                av[mt * 2 + kt] = *(const short8*)(Ab + (size_t)mt * 16 * NN + kt * 32 + j0);
    };
    auto pstep = [&](const float2* ev, const short8* av, int j0, int buf) {
        float2 st = stL[j0 + jl];
#pragma unroll
        for (int q = 0; q < 16; ++q) {
            float edge = e ? ev[q].y : ev[q].x;
            float x = s1r[q] + st.x;
            x = x >= 0.f ? x : 0.2f * x;
            pA[buf][(ib * 16 + q) * 72 + jl] = f2bf(__expf(x + edge) * st.y);
        }
        __syncthreads();
        short8 bv[4][2];
#pragma unroll
        for (int nt = 0; nt < 4; ++nt)
#pragma unroll
            for (int kt = 0; kt < 2; ++kt)
                bv[nt][kt] = *(const short8*)&pA[buf][(nt * 16 + n) * 72 + kt * 32 + quad * 8];
#pragma unroll
        for (int kt = 0; kt < 2; ++kt)
#pragma unroll
            for (int mt = 0; mt < 2; ++mt)
#pragma unroll
                for (int nt = 0; nt < 4; ++nt)
                    acc[mt][nt] = __builtin_amdgcn_mfma_f32_16x16x32_bf16(
                        av[mt * 2 + kt], bv[nt][kt], acc[mt][nt], 0, 0, 0);
    };

    loadE(evA, 0);
    loadA(aA, 0);
    for (int sp2 = 0; sp2 < 8; ++sp2) {
        int j0 = sp2 * 128;
        loadE(evB, j0 + 64);
        loadA(aB, j0 + 64);
        pstep(evA, aA, j0, 0);
        if (sp2 < 7) {
            loadE(evA, j0 + 128);
            loadA(aA, j0 + 128);
        }
        pstep(evB, aB, j0 + 64, 1);
    }

    // epilogue: C row(quad*4+r)=d, col(lane&15)=i-local
#pragma unroll
    for (int mt = 0; mt < 2; ++mt) {
        int d0 = w * 32 + mt * 16 + quad * 4;
        f32x4 sbv = *(const f32x4*)&sb[eh * ND + d0];
#pragma unroll
        for (int nt = 0; nt < 4; ++nt) {
            int i = i0 + nt * 16 + n;
            if (mode == 0) {
                union { unsigned short us[4]; unsigned long long u64; } pk;
#pragma unroll
                for (int r = 0; r < 4; ++r) pk.us[r] = f2bf(acc[mt][nt][r] + sbv[r]);
                *(unsigned long long*)(out0 + (size_t)(b * NN + i) * FIN1 + eh * ND + d0) =
                    pk.u64;
            } else {
                f32x4 vv;
#pragma unroll
                for (int r = 0; r < 4; ++r) {
                    float v = acc[mt][nt][r] + sbv[r];
                    vv[r] = v > 0.f ? v : expm1f(v);
                }
                *(f32x4*)(out1 + ((size_t)(eh * NB + b) * NN + i) * ND + d0) = vv;
            }
        }
    }
}

// ---------------- final: out = mean_eh(m1) @ Wout + bout (fused) ----------------
__global__ __launch_bounds__(256) void finalk(const float* __restrict__ m1,
                                              const float* __restrict__ Wout,
                                              const float* __restrict__ bout,
                                              float* __restrict__ out) {
    int row0 = blockIdx.x * 16;
    int t = threadIdx.x;
    __shared__ float sF[16 * ND];
    __shared__ float wL[ND * NO];
    const size_t str = (size_t)BN * ND;
    for (int idx = t; idx < 16 * ND; idx += 256) {
        size_t r = (size_t)row0 * ND + idx;
        sF[idx] = 0.25f * (m1[r] + m1[r + str] + m1[r + 2 * str] + m1[r + 3 * str]);
    }
    for (int idx = t; idx < ND * NO; idx += 256) wL[idx] = Wout[idx];
    __syncthreads();
    int o = t & 63;
    int rr = t >> 6;
    float bo = bout[o];
#pragma unroll
    for (int q = 0; q < 4; ++q) {
        int r = rr * 4 + q;
        float acc = 0.f;
#pragma unroll 4
        for (int d = 0; d < ND; ++d) acc += sF[r * ND + d] * wL[d * NO + o];
        out[(size_t)(row0 + r) * NO + o] = acc + bo;
    }
}

extern "C" void kernel_launch(void* const* d_in, const int* in_sizes, int n_in,
                              void* d_out, int out_size, void* d_ws, size_t ws_size,
                              hipStream_t stream) {
    const float* nodes = (const float*)d_in[0];
    const float* edges = (const float*)d_in[1];
    const float* Wemb = (const float*)d_in[2];
    const float* bemb = (const float*)d_in[3];
    const float* W0 = (const float*)d_in[4];
    const float* A1w0 = (const float*)d_in[5];
    const float* A1b0 = (const float*)d_in[6];
    const float* A2w0 = (const float*)d_in[7];
    const float* A2b0 = (const float*)d_in[8];
    const float* SB0 = (const float*)d_in[9];
    const float* W1 = (const float*)d_in[10];
    const float* A1w1 = (const float*)d_in[11];
    const float* A1b1 = (const float*)d_in[12];
    const float* A2w1 = (const float*)d_in[13];
    const float* A2b1 = (const float*)d_in[14];
    const float* SB1 = (const float*)d_in[15];
    const float* Wout = (const float*)d_in[16];
    const float* bout = (const float*)d_in[17];
    float* out = (float*)d_out;

    char* p = (char*)d_ws;
    auto alloc = [&](size_t bytes) {
        char* r = p;
        p += (bytes + 255) & ~(size_t)255;
        return r;
    };
    unsigned short* state0 = (unsigned short*)alloc((size_t)BN * ND * 2);
    unsigned short* W0T = (unsigned short*)alloc((size_t)EHC * ND * ND * 2);
    unsigned short* W1T = (unsigned short*)alloc((size_t)EHC * ND * FIN1 * 2);
    unsigned short* WhT = (unsigned short*)alloc((size_t)EHC * BN * ND * 2);
    unsigned short* state1 = (unsigned short*)alloc((size_t)BN * FIN1 * 2);
    float* s1b = (float*)alloc((size_t)EHC * BN * 4);
    float* s2b = (float*)alloc((size_t)EHC * BN * 4);
    float* Spart = (float*)alloc((size_t)4 * EHC * BN * 4);
    float* m1 = (float*)alloc((size_t)EHC * BN * ND * 4);

    prepTk<<<1280, 256, 0, stream>>>(W0, W1, W0T, W1T);
    embedk<<<BN / 16, 256, 0, stream>>>(nodes, Wemb, bemb, state0);
    // layer 0
    whgemmk<ND><<<dim3(BN / 64, EHC), 256, 0, stream>>>(state0, W0T, WhT);
    s1s2k<<<512, 256, 0, stream>>>(WhT, A1w0, A1b0, A2w0, A2b0, s1b, s2b);
    colsumk<<<dim3(NN / 64, NB, 4), 256, 0, stream>>>(edges, s1b, s2b, Spart);
    msgk<<<dim3(EHC, NN / 64, NB), 256, 0, stream>>>(edges, WhT, s1b, s2b, Spart, SB0,
                                                     state1, m1, 0);
    // layer 1
    whgemmk<FIN1><<<dim3(BN / 64, EHC), 256, 0, stream>>>(state1, W1T, WhT);
    s1s2k<<<512, 256, 0, stream>>>(WhT, A1w1, A1b1, A2w1, A2b1, s1b, s2b);
    colsumk<<<dim3(NN / 64, NB, 4), 256, 0, stream>>>(edges, s1b, s2b, Spart);
    msgk<<<dim3(EHC, NN / 64, NB), 256, 0, stream>>>(edges, WhT, s1b, s2b, Spart, SB1,
                                                     state1, m1, 1);
    // head
    finalk<<<BN / 16, 256, 0, stream>>>(m1, Wout, bout, out);
}